// Round 11
// baseline (107.412 us; speedup 1.0000x reference)
//
#include <hip/hip_runtime.h>

// SASA plain 3-kernel pipeline, R14: R12 anchor + ONLY the p1 A-stride bank fix.
// B=2, CIN=192, HW=3136, 6 heads x d=32, 7x7 window.
// Cost model: dur_us = kernels + ws-poison fills (2x256MiB @~42.5us = health gauge).
// History: R9=105.6 | R12=104.0 (dot2-bf16 QK + pk_fma PV, f32-V stride 36) |
//   R13b=106.6 (fills 42.8): f16-paired-V PV + A-stride fix bundled = +1.5-2us
//   REAL regression, un-attributable -> this round isolates.
// R14 = R12 with exactly one change:
//   p1 As row stride 100->101 dw (202 ush). Old A-staging writes: lane stride
//   400 dw, 400%32=16 -> 8 banks x 8-deep = 2.94x cost. New: 404%32=20,
//   gcd(20,32)=4 -> all 32 banks x 2-deep = free. MFMA-read side stays ~8/bank
//   uniform (101 is odd -> 5r mod 32 covers all residues). Math bit-identical.
// Discriminator: ~103.5 => R13's regression was the f16-V PV (stays dead);
//   ~106 => stride fix itself regresses (revert + fix bank model).
//
// ws layout (bytes):
//   QKV  [6272][576] bf16 @ 0        q ch 0-191 | k 192-383 | v 384-575
//   OACT [6272][192] bf16 @ 7225344  attention out = proj B-operand

#define HW    3136
#define WIMG  56
#define CIN   192
#define QKVLD 576
#define SMEM_P1 51456
#define SMEM_P2 43904
#define LOG2E 1.44269504088896340736f

using short8 = __attribute__((ext_vector_type(8))) short;
using f32x4  = __attribute__((ext_vector_type(4))) float;

// packed RTNE f32x2 -> bf16x2, single HW instruction (lo = a, hi = b)
__device__ __forceinline__ unsigned pack2(float a, float b) {
    unsigned r;
    asm("v_cvt_pk_bf16_f32 %0, %1, %2" : "=v"(r) : "v"(a), "v"(b));
    return r;
}
__device__ __forceinline__ float bflo(unsigned u) {
    union { unsigned u; float f; } v; v.u = u << 16; return v.f;
}
__device__ __forceinline__ float bfhi(unsigned u) {
    union { unsigned u; float f; } v; v.u = u & 0xffff0000u; return v.f;
}
// D = S0.bf16[0]*S1.bf16[0] + S0.bf16[1]*S1.bf16[1] + S2   (exact products, f32 acc)
__device__ __forceinline__ float dot2bf(unsigned k2, unsigned q2, float c) {
    float d;
    asm("v_dot2_f32_bf16 %0, %1, %2, %3" : "=v"(d) : "v"(k2), "v"(q2), "v"(c));
    return d;
}
// packed dual f32 fma: d.lo = a.lo*b.lo + c.lo ; d.hi = a.hi*b.hi + c.hi
__device__ __forceinline__ float2 pkfma(float2 a, float2 b, float2 c) {
    float2 d;
    asm("v_pk_fma_f32 %0, %1, %2, %3" : "=v"(d) : "v"(a), "v"(b), "v"(c));
    return d;
}
// quad-of-4 butterfly sum via DPP quad_perm (VALU pipe, not ds_swizzle/LDS).
__device__ __forceinline__ float qsum4(float s) {
    union { float f; int i; } u, t;
    u.f = s;
    t.i = __builtin_amdgcn_update_dpp(0, u.i, 0xB1, 0xF, 0xF, true); // xor 1
    u.f += t.f;
    t.i = __builtin_amdgcn_update_dpp(0, u.i, 0x4E, 0xF, 0xF, true); // xor 2
    u.f += t.f;
    return u.f;
}

// ======================= Phase 1: QKV GEMM tile =============================
// t in [0,882): mt = t%98 (64-pixel strip over b,p), nt = t/98 (64 of 576 out ch).
__global__ __launch_bounds__(256) void k_p1(
    const float* __restrict__ x, const float* __restrict__ wq,
    const float* __restrict__ wk, const float* __restrict__ wv,
    unsigned short* __restrict__ qkv)
{
    extern __shared__ char smem[];
    unsigned short* As  = (unsigned short*)smem;     // 64 x 202 ushorts (R14)
    unsigned short* Bs  = As + 64 * 202;             // 64 x 200 ushorts
    unsigned*       Asw = (unsigned*)smem;           // dword view, row stride 101
    unsigned*       Bsw = (unsigned*)(smem + 25856);

    const int tid = threadIdx.x;
    const int lane = tid & 63, wave = tid >> 6;
    const int l15  = lane & 15, quad = lane >> 4;
    const int wm   = (wave & 1) * 32, wn = (wave >> 1) * 32;

    const int t = blockIdx.x;
    const int mt = t % 98, nt = t / 98;
    const int m0 = mt * 64, n0 = nt * 64;
    const float* Wp = (nt < 3) ? (wq + (size_t)n0 * CIN)
                    : (nt < 6) ? (wk + (size_t)(n0 - 192) * CIN)
                               : (wv + (size_t)(n0 - 384) * CIN);

    #pragma unroll
    for (int i = 0; i < 6; ++i) {
        int u = tid + 256 * i;
        int pq = u & 15, c2 = u >> 4;            // pq: p-quad 0..15, c2: 0..95
        int pp = m0 + pq * 4;
        int bb = (pp >= HW) ? 1 : 0;
        const float* src = x + ((size_t)(bb * CIN + c2 * 2)) * HW + (pp - bb * HW);
        float4 f0 = *(const float4*)src;          // c = c2*2,   p..p+3
        float4 f1 = *(const float4*)(src + HW);   // c = c2*2+1, p..p+3
        Asw[(pq * 4 + 0) * 101 + c2] = pack2(f0.x, f1.x);
        Asw[(pq * 4 + 1) * 101 + c2] = pack2(f0.y, f1.y);
        Asw[(pq * 4 + 2) * 101 + c2] = pack2(f0.z, f1.z);
        Asw[(pq * 4 + 3) * 101 + c2] = pack2(f0.w, f1.w);
    }
    {
        int o = tid >> 2, c4 = tid & 3;
        #pragma unroll
        for (int i = 0; i < 12; ++i) {
            int cq = c4 + 4 * i;                 // 0..47
            float4 w = *(const float4*)(Wp + (size_t)o * CIN + cq * 4);
            uint2 d; d.x = pack2(w.x, w.y); d.y = pack2(w.z, w.w);
            *(uint2*)(Bsw + o * 100 + cq * 2) = d;
        }
    }
    __syncthreads();

    f32x4 acc[2][2] = {};
    const unsigned short* pa0 = As + (wm + l15) * 202 + quad * 8;
    const unsigned short* pb0 = Bs + (wn + l15) * 200 + quad * 8;
    #pragma unroll
    for (int s = 0; s < 6; ++s) {
        short8 a0 = *(const short8*)(pa0 + s * 32);
        short8 a1 = *(const short8*)(pa0 + 16 * 202 + s * 32);
        short8 b0 = *(const short8*)(pb0 + s * 32);
        short8 b1 = *(const short8*)(pb0 + 16 * 200 + s * 32);
        acc[0][0] = __builtin_amdgcn_mfma_f32_16x16x32_bf16(a0, b0, acc[0][0], 0, 0, 0);
        acc[0][1] = __builtin_amdgcn_mfma_f32_16x16x32_bf16(a0, b1, acc[0][1], 0, 0, 0);
        acc[1][0] = __builtin_amdgcn_mfma_f32_16x16x32_bf16(a1, b0, acc[1][0], 0, 0, 0);
        acc[1][1] = __builtin_amdgcn_mfma_f32_16x16x32_bf16(a1, b1, acc[1][1], 0, 0, 0);
    }

    const int gm = m0 + wm + quad * 4;   // global pixel row
    const int gn = n0 + wn + l15;        // output channel (0..575)
    #pragma unroll
    for (int ti = 0; ti < 2; ++ti)
        #pragma unroll
        for (int tj = 0; tj < 2; ++tj)
            #pragma unroll
            for (int rr = 0; rr < 4; rr += 2) {
                unsigned r = pack2(acc[ti][tj][rr], acc[ti][tj][rr + 1]);
                qkv[(size_t)(gm + ti * 16 + rr) * QKVLD + (gn + tj * 16)] =
                    (unsigned short)r;
                qkv[(size_t)(gm + ti * 16 + rr + 1) * QKVLD + (gn + tj * 16)] =
                    (unsigned short)(r >> 16);
            }
}

// ======================= Phase 2: windowed attention ========================
// t in [0,588): 49 8x8-pixel tiles x 12 (b,h). 4 threads/pixel (d split 4x8).
// K raw bf16 in LDS (stride 40 shorts), consumed by v_dot2_f32_bf16.
// V f32 in LDS (stride 36 floats), consumed by v_pk_fma_f32.  (= R12 exactly)
__global__ __launch_bounds__(256) void k_p2(
    const unsigned short* __restrict__ qkv, const float* __restrict__ pos,
    unsigned short* __restrict__ oact)
{
    extern __shared__ char smem[];
    unsigned short* kbufB = (unsigned short*)smem;      // [196 px][32 ch] stride 40
    float*          vbuf  = (float*)(smem + 196 * 40 * 2); // [196 px][32 ch] stride 36

    const int tid = threadIdx.x;
    const int t = blockIdx.x;
    const int tz = t / 49, r49 = t - tz * 49;
    const int ty = r49 / 7, tx = r49 - ty * 7;
    const int bq = tz / 6, h = tz - bq * 6;
    const int y0 = ty * 8 - 3, x0 = tx * 8 - 3;

    const int sub = tid & 3, pix = tid >> 2;
    const int py = pix >> 3, px = pix & 7;
    const int y = ty * 8 + py, xx = tx * 8 + px;
    const int p = y * WIMG + xx;

    // Q (raw packed bf16) + pos hoisted above staging
    uint4 qv = *(const uint4*)(qkv + (size_t)(bq * HW + p) * QKVLD + h * 32 + sub * 8);
    float posE[13];
    #pragma unroll
    for (int i = 0; i < 13; ++i) posE[i] = pos[i] * LOG2E;

    // unified K+V staging: 1568 uint4 units = 196 px * (4 k + 4 v)
    #pragma unroll
    for (int i = 0; i < 7; ++i) {
        int u = tid + 256 * i;
        if (u < 1568) {
            int pp = u >> 3, uu = u & 7;
            int part = uu >> 2, sub8 = uu & 3;       // part 0=k, 1=v
            int ppy = pp / 14, ppx = pp - ppy * 14;
            int gy = y0 + ppy, gx = x0 + ppx;
            uint4 rv = make_uint4(0u, 0u, 0u, 0u);
            if ((unsigned)gy < 56u && (unsigned)gx < 56u)
                rv = *(const uint4*)(qkv +
                    (size_t)(bq * HW + gy * WIMG + gx) * QKVLD +
                    192 + part * 192 + h * 32 + sub8 * 8);
            if (part == 0) {
                // K: raw bf16 copy, no unpack
                *(uint4*)(kbufB + pp * 40 + sub8 * 8) = rv;
            } else {
                // V: unpack to f32, stride 36 (16B-aligned rows)
                float4 vA, vB;
                vA.x=bflo(rv.x); vA.y=bfhi(rv.x); vA.z=bflo(rv.y); vA.w=bfhi(rv.y);
                vB.x=bflo(rv.z); vB.y=bfhi(rv.z); vB.z=bflo(rv.w); vB.w=bfhi(rv.w);
                float* dst = vbuf + pp * 36 + sub8 * 8;
                *(float4*)(dst + 0) = vA;
                *(float4*)(dst + 4) = vB;
            }
        }
    }
    __syncthreads();

    const unsigned short* kr = kbufB + sub * 8;

    float logits[49];
    #pragma unroll
    for (int kk = 0; kk < 49; ++kk) {
        const int ky = kk / 7, kx = kk % 7;
        const int pp = (py + ky) * 14 + (px + kx);
        uint4 kv = *(const uint4*)(kr + pp * 40);
        float s = 0.f;
        s = dot2bf(kv.x, qv.x, s);
        s = dot2bf(kv.y, qv.y, s);
        s = dot2bf(kv.z, qv.z, s);
        s = dot2bf(kv.w, qv.w, s);
        logits[kk] = fmaf(qsum4(s), LOG2E, posE[ky + kx]);
    }

    float m = logits[0];
    #pragma unroll
    for (int kk = 1; kk < 49; ++kk) m = fmaxf(m, logits[kk]);
    float sum = 0.f;
    #pragma unroll
    for (int kk = 0; kk < 49; ++kk) {
        logits[kk] = __builtin_amdgcn_exp2f(logits[kk] - m);
        sum += logits[kk];
    }

    float2 a01 = make_float2(0.f, 0.f), a23 = make_float2(0.f, 0.f);
    float2 a45 = make_float2(0.f, 0.f), a67 = make_float2(0.f, 0.f);
    #pragma unroll
    for (int kk = 0; kk < 49; ++kk) {
        const int ky = kk / 7, kx = kk % 7;
        const int pp = (py + ky) * 14 + (px + kx);
        const float4* vp = (const float4*)(vbuf + pp * 36 + sub * 8);
        float4 vA = vp[0], vB = vp[1];
        const float pw = logits[kk];
        const float2 pw2 = make_float2(pw, pw);
        a01 = pkfma(make_float2(vA.x, vA.y), pw2, a01);
        a23 = pkfma(make_float2(vA.z, vA.w), pw2, a23);
        a45 = pkfma(make_float2(vB.x, vB.y), pw2, a45);
        a67 = pkfma(make_float2(vB.z, vB.w), pw2, a67);
    }
    const float inv = 1.f / sum;

    uint4 o;
    o.x = pack2(a01.x * inv, a01.y * inv);
    o.y = pack2(a23.x * inv, a23.y * inv);
    o.z = pack2(a45.x * inv, a45.y * inv);
    o.w = pack2(a67.x * inv, a67.y * inv);
    *(uint4*)(oact + (size_t)(bq * HW + p) * CIN + h * 32 + sub * 8) = o;
}

// ======================= Phase 3: projection tile ===========================
// t in [0,294): mt = t%3 (64 out ch), pt = t/3 (64-pixel strip).
__global__ __launch_bounds__(256) void k_p3(
    const float* __restrict__ wproj, const unsigned short* __restrict__ oact,
    float* __restrict__ out)
{
    extern __shared__ char smem[];
    unsigned short* As  = (unsigned short*)smem;
    unsigned short* Bs  = As + 64 * 200;
    unsigned*       Asw = (unsigned*)smem;

    const int tid = threadIdx.x;
    const int lane = tid & 63, wave = tid >> 6;
    const int l15  = lane & 15, quad = lane >> 4;
    const int wm   = (wave & 1) * 32, wn = (wave >> 1) * 32;

    const int t = blockIdx.x;
    const int mt = t % 3, pt = t / 3;
    {
        int o = tid >> 2, c4 = tid & 3;
        #pragma unroll
        for (int i = 0; i < 12; ++i) {
            int cq = c4 + 4 * i;
            float4 w = *(const float4*)(wproj + (size_t)(mt * 64 + o) * CIN + cq * 4);
            uint2 d; d.x = pack2(w.x, w.y); d.y = pack2(w.z, w.w);
            *(uint2*)(Asw + o * 100 + cq * 2) = d;
        }
    }
    {
        int rw = tid >> 2, s4 = tid & 3;
        #pragma unroll
        for (int i = 0; i < 6; ++i) {
            int seg = s4 + 4 * i;               // 0..23
            uint4 dv = *(const uint4*)(oact + (size_t)(pt * 64 + rw) * CIN + seg * 8);
            *(uint4*)(Bs + rw * 200 + seg * 8) = dv;
        }
    }
    __syncthreads();

    f32x4 acc[2][2] = {};
    const unsigned short* pa0 = As + (wm + l15) * 200 + quad * 8;
    const unsigned short* pb0 = Bs + (wn + l15) * 200 + quad * 8;
    #pragma unroll
    for (int s = 0; s < 6; ++s) {
        short8 a0 = *(const short8*)(pa0 + s * 32);
        short8 a1 = *(const short8*)(pa0 + 16 * 200 + s * 32);
        short8 b0 = *(const short8*)(pb0 + s * 32);
        short8 b1 = *(const short8*)(pb0 + 16 * 200 + s * 32);
        acc[0][0] = __builtin_amdgcn_mfma_f32_16x16x32_bf16(a0, b0, acc[0][0], 0, 0, 0);
        acc[0][1] = __builtin_amdgcn_mfma_f32_16x16x32_bf16(a0, b1, acc[0][1], 0, 0, 0);
        acc[1][0] = __builtin_amdgcn_mfma_f32_16x16x32_bf16(a1, b0, acc[1][0], 0, 0, 0);
        acc[1][1] = __builtin_amdgcn_mfma_f32_16x16x32_bf16(a1, b1, acc[1][1], 0, 0, 0);
    }

    const int bb = (pt * 64 >= HW) ? 1 : 0;
    const int pl = pt * 64 - bb * HW + wn + l15;      // col = pixel within batch
    const int go = mt * 64 + wm + quad * 4;           // row = output channel
    float* Yb = out + (size_t)bb * (CIN * HW);
    #pragma unroll
    for (int ti = 0; ti < 2; ++ti)
        #pragma unroll
        for (int tj = 0; tj < 2; ++tj)
            #pragma unroll
            for (int rr = 0; rr < 4; ++rr)
                Yb[(size_t)(go + ti * 16 + rr) * HW + pl + tj * 16] = acc[ti][tj][rr];
}

// ---------------------------------------------------------------------------
extern "C" void kernel_launch(void* const* d_in, const int* in_sizes, int n_in,
                              void* d_out, int out_size, void* d_ws, size_t ws_size,
                              hipStream_t stream)
{
    const float* x     = (const float*)d_in[0];
    const float* wq    = (const float*)d_in[1];
    const float* wk    = (const float*)d_in[2];
    const float* wv    = (const float*)d_in[3];
    const float* pos   = (const float*)d_in[4];
    const float* wproj = (const float*)d_in[5];

    char* ws = (char*)d_ws;
    unsigned short* qkvp  = (unsigned short*)ws;
    unsigned short* oactp = (unsigned short*)(ws + 7225344);
    float*          outp  = (float*)d_out;

    k_p1<<<dim3(882), dim3(256), SMEM_P1, stream>>>(x, wq, wk, wv, qkvp);
    k_p2<<<dim3(588), dim3(256), SMEM_P2, stream>>>(qkvp, pos, oactp);
    k_p3<<<dim3(294), dim3(256), SMEM_P1, stream>>>(wproj, oactp, outp);
}

// Round 12
// 103.578 us; speedup vs baseline: 1.0370x; 1.0370x over previous
//
#include <hip/hip_runtime.h>

// SASA plain 3-kernel pipeline, R15: R12 p1/p3 (stride-100 anchor) + f16-paired-V p2.
// B=2, CIN=192, HW=3136, 6 heads x d=32, 7x7 window.
// Cost model: dur_us = kernels + ws-poison fills (2x256MiB @~42.5us = health gauge).
// History: R12=104.0 anchor | R13b=106.6 (stride101 p1 + f16V p2) | R14=107.4
//   (stride101 p1 + f32V p2, fills healthy) => stride-101 CONVICTED: 404B row
//   stride breaks 16B provable alignment -> ds_read_b128 shatters to 4x b32 in
//   the MFMA loop (+3.4us). LESSON: LDS row strides for b128 tiles must be
//   multiples of 16B. R13b-R14 pairwise (same p1, p2 differs): f16-paired-V p2
//   is GOOD for ~1us and absmax-neutral.
// R15 = R12 p1/p3 verbatim + R13b p2 verbatim:
//   p2: K raw bf16 (stride 40 ush) via v_dot2_f32_bf16; V as f16 PAIRS of
//   adjacent pixels (vpb[98][36 dw], dword = (V[even],V[odd]) per ch) via
//   v_dot2_f32_f16 with pkh-packed weight pairs. V LDS bytes/thread -48%,
//   V-read instrs 98->56, LDS 29.8KB, no unpack VALU.
//
// ws layout (bytes):
//   QKV  [6272][576] bf16 @ 0        q ch 0-191 | k 192-383 | v 384-575
//   OACT [6272][192] bf16 @ 7225344  attention out = proj B-operand

#define HW    3136
#define WIMG  56
#define CIN   192
#define QKVLD 576
#define SMEM_P1 53312
#define SMEM_P2 29792
#define LOG2E 1.44269504088896340736f

using short8 = __attribute__((ext_vector_type(8))) short;
using f32x4  = __attribute__((ext_vector_type(4))) float;

// packed RTNE f32x2 -> bf16x2, single HW instruction (lo = a, hi = b)
__device__ __forceinline__ unsigned pack2(float a, float b) {
    unsigned r;
    asm("v_cvt_pk_bf16_f32 %0, %1, %2" : "=v"(r) : "v"(a), "v"(b));
    return r;
}
// packed f32x2 -> f16x2 (RTZ), single HW instruction (lo = a, hi = b)
__device__ __forceinline__ unsigned pkh(float a, float b) {
    unsigned r;
    asm("v_cvt_pkrtz_f16_f32 %0, %1, %2" : "=v"(r) : "v"(a), "v"(b));
    return r;
}
__device__ __forceinline__ float bflo(unsigned u) {
    union { unsigned u; float f; } v; v.u = u << 16; return v.f;
}
__device__ __forceinline__ float bfhi(unsigned u) {
    union { unsigned u; float f; } v; v.u = u & 0xffff0000u; return v.f;
}
// D = S0.bf16[0]*S1.bf16[0] + S0.bf16[1]*S1.bf16[1] + S2  (exact products)
__device__ __forceinline__ float dot2bf(unsigned k2, unsigned q2, float c) {
    float d;
    asm("v_dot2_f32_bf16 %0, %1, %2, %3" : "=v"(d) : "v"(k2), "v"(q2), "v"(c));
    return d;
}
// D = S0.f16[0]*S1.f16[0] + S0.f16[1]*S1.f16[1] + S2
__device__ __forceinline__ float dot2h(unsigned v2, unsigned w2, float c) {
    float d;
    asm("v_dot2_f32_f16 %0, %1, %2, %3" : "=v"(d) : "v"(v2), "v"(w2), "v"(c));
    return d;
}
// quad-of-4 butterfly sum via DPP quad_perm (VALU pipe, not ds_swizzle/LDS).
__device__ __forceinline__ float qsum4(float s) {
    union { float f; int i; } u, t;
    u.f = s;
    t.i = __builtin_amdgcn_update_dpp(0, u.i, 0xB1, 0xF, 0xF, true); // xor 1
    u.f += t.f;
    t.i = __builtin_amdgcn_update_dpp(0, u.i, 0x4E, 0xF, 0xF, true); // xor 2
    u.f += t.f;
    return u.f;
}

// ======================= Phase 1: QKV GEMM tile =============================
// t in [0,882): mt = t%98 (64-pixel strip over b,p), nt = t/98 (64 of 576 out ch).
// R12 version verbatim: As stride 100 dw (400B, 16B-aligned -> b128 reads intact).
__global__ __launch_bounds__(256) void k_p1(
    const float* __restrict__ x, const float* __restrict__ wq,
    const float* __restrict__ wk, const float* __restrict__ wv,
    unsigned short* __restrict__ qkv)
{
    extern __shared__ char smem[];
    unsigned short* As  = (unsigned short*)smem;     // 64 x 200 ushorts
    unsigned short* Bs  = As + 64 * 200;
    unsigned*       Asw = (unsigned*)smem;           // dword view, row stride 100
    unsigned*       Bsw = (unsigned*)(smem + 25600);

    const int tid = threadIdx.x;
    const int lane = tid & 63, wave = tid >> 6;
    const int l15  = lane & 15, quad = lane >> 4;
    const int wm   = (wave & 1) * 32, wn = (wave >> 1) * 32;

    const int t = blockIdx.x;
    const int mt = t % 98, nt = t / 98;
    const int m0 = mt * 64, n0 = nt * 64;
    const float* Wp = (nt < 3) ? (wq + (size_t)n0 * CIN)
                    : (nt < 6) ? (wk + (size_t)(n0 - 192) * CIN)
                               : (wv + (size_t)(n0 - 384) * CIN);

    #pragma unroll
    for (int i = 0; i < 6; ++i) {
        int u = tid + 256 * i;
        int pq = u & 15, c2 = u >> 4;            // pq: p-quad 0..15, c2: 0..95
        int pp = m0 + pq * 4;
        int bb = (pp >= HW) ? 1 : 0;
        const float* src = x + ((size_t)(bb * CIN + c2 * 2)) * HW + (pp - bb * HW);
        float4 f0 = *(const float4*)src;          // c = c2*2,   p..p+3
        float4 f1 = *(const float4*)(src + HW);   // c = c2*2+1, p..p+3
        Asw[(pq * 4 + 0) * 100 + c2] = pack2(f0.x, f1.x);
        Asw[(pq * 4 + 1) * 100 + c2] = pack2(f0.y, f1.y);
        Asw[(pq * 4 + 2) * 100 + c2] = pack2(f0.z, f1.z);
        Asw[(pq * 4 + 3) * 100 + c2] = pack2(f0.w, f1.w);
    }
    {
        int o = tid >> 2, c4 = tid & 3;
        #pragma unroll
        for (int i = 0; i < 12; ++i) {
            int cq = c4 + 4 * i;                 // 0..47
            float4 w = *(const float4*)(Wp + (size_t)o * CIN + cq * 4);
            uint2 d; d.x = pack2(w.x, w.y); d.y = pack2(w.z, w.w);
            *(uint2*)(Bsw + o * 100 + cq * 2) = d;
        }
    }
    __syncthreads();

    f32x4 acc[2][2] = {};
    const unsigned short* pa0 = As + (wm + l15) * 200 + quad * 8;
    const unsigned short* pb0 = Bs + (wn + l15) * 200 + quad * 8;
    #pragma unroll
    for (int s = 0; s < 6; ++s) {
        short8 a0 = *(const short8*)(pa0 + s * 32);
        short8 a1 = *(const short8*)(pa0 + 16 * 200 + s * 32);
        short8 b0 = *(const short8*)(pb0 + s * 32);
        short8 b1 = *(const short8*)(pb0 + 16 * 200 + s * 32);
        acc[0][0] = __builtin_amdgcn_mfma_f32_16x16x32_bf16(a0, b0, acc[0][0], 0, 0, 0);
        acc[0][1] = __builtin_amdgcn_mfma_f32_16x16x32_bf16(a0, b1, acc[0][1], 0, 0, 0);
        acc[1][0] = __builtin_amdgcn_mfma_f32_16x16x32_bf16(a1, b0, acc[1][0], 0, 0, 0);
        acc[1][1] = __builtin_amdgcn_mfma_f32_16x16x32_bf16(a1, b1, acc[1][1], 0, 0, 0);
    }

    const int gm = m0 + wm + quad * 4;   // global pixel row
    const int gn = n0 + wn + l15;        // output channel (0..575)
    #pragma unroll
    for (int ti = 0; ti < 2; ++ti)
        #pragma unroll
        for (int tj = 0; tj < 2; ++tj)
            #pragma unroll
            for (int rr = 0; rr < 4; rr += 2) {
                unsigned r = pack2(acc[ti][tj][rr], acc[ti][tj][rr + 1]);
                qkv[(size_t)(gm + ti * 16 + rr) * QKVLD + (gn + tj * 16)] =
                    (unsigned short)r;
                qkv[(size_t)(gm + ti * 16 + rr + 1) * QKVLD + (gn + tj * 16)] =
                    (unsigned short)(r >> 16);
            }
}

// ======================= Phase 2: windowed attention ========================
// t in [0,588): 49 8x8-pixel tiles x 12 (b,h). 4 threads/pixel (d split 4x8).
// K raw bf16 LDS (stride 40 ush) via v_dot2_f32_bf16.
// V as f16 PAIRS of adjacent pixels: vpb[98 pairs][32 ch dwords] stride 36 dw;
// dword(ch) = (V[even px], V[odd px]); PV via v_dot2_f32_f16.  (= R13b verbatim)
__global__ __launch_bounds__(256) void k_p2(
    const unsigned short* __restrict__ qkv, const float* __restrict__ pos,
    unsigned short* __restrict__ oact)
{
    extern __shared__ char smem[];
    unsigned short* kbufB = (unsigned short*)smem;            // 196 x 40 ush
    unsigned*       vpb   = (unsigned*)(smem + 196 * 40 * 2); // 98 x 36 dw

    const int tid = threadIdx.x;
    const int t = blockIdx.x;
    const int tz = t / 49, r49 = t - tz * 49;
    const int ty = r49 / 7, tx = r49 - ty * 7;
    const int bq = tz / 6, h = tz - bq * 6;
    const int y0 = ty * 8 - 3, x0 = tx * 8 - 3;

    const int sub = tid & 3, pix = tid >> 2;
    const int py = pix >> 3, px = pix & 7;
    const int y = ty * 8 + py, xx = tx * 8 + px;
    const int p = y * WIMG + xx;

    // Q (raw packed bf16) + pos hoisted above staging
    uint4 qv = *(const uint4*)(qkv + (size_t)(bq * HW + p) * QKVLD + h * 32 + sub * 8);
    float posE[13];
    #pragma unroll
    for (int i = 0; i < 13; ++i) posE[i] = pos[i] * LOG2E;

    // staging: 784 K units (196 px x 4 ch-groups, raw bf16 copy)
    //        + 392 V pair units (98 pairs x 4 ch-groups, bf16->f16 interleave)
    #pragma unroll
    for (int i = 0; i < 5; ++i) {
        int u = tid + 256 * i;
        if (u < 784) {
            int pp = u >> 2, sub8 = u & 3;
            int ppy = pp / 14, ppx = pp - ppy * 14;
            int gy = y0 + ppy, gx = x0 + ppx;
            uint4 rv = make_uint4(0u, 0u, 0u, 0u);
            if ((unsigned)gy < 56u && (unsigned)gx < 56u)
                rv = *(const uint4*)(qkv +
                    (size_t)(bq * HW + gy * WIMG + gx) * QKVLD +
                    192 + h * 32 + sub8 * 8);
            *(uint4*)(kbufB + pp * 40 + sub8 * 8) = rv;
        } else if (u < 1176) {
            int vu = u - 784;
            int pr = vu >> 2, cg = vu & 3;
            int rowy = pr / 7, pc = pr - rowy * 7;
            int gy = y0 + rowy, gxe = x0 + 2 * pc;
            uint4 a = make_uint4(0u,0u,0u,0u), b = make_uint4(0u,0u,0u,0u);
            const bool oky = (unsigned)gy < 56u;
            const unsigned short* vs = qkv +
                (size_t)(bq * HW + gy * WIMG + gxe) * QKVLD + 384 + h * 32 + cg * 8;
            if (oky && (unsigned)gxe < 56u)       a = *(const uint4*)vs;
            if (oky && (unsigned)(gxe + 1) < 56u) b = *(const uint4*)(vs + QKVLD);
            unsigned d0 = pkh(bflo(a.x), bflo(b.x));
            unsigned d1 = pkh(bfhi(a.x), bfhi(b.x));
            unsigned d2 = pkh(bflo(a.y), bflo(b.y));
            unsigned d3 = pkh(bfhi(a.y), bfhi(b.y));
            unsigned d4 = pkh(bflo(a.z), bflo(b.z));
            unsigned d5 = pkh(bfhi(a.z), bfhi(b.z));
            unsigned d6 = pkh(bflo(a.w), bflo(b.w));
            unsigned d7 = pkh(bfhi(a.w), bfhi(b.w));
            unsigned* dst = vpb + pr * 36 + cg * 8;
            *(uint4*)(dst)     = make_uint4(d0, d1, d2, d3);
            *(uint4*)(dst + 4) = make_uint4(d4, d5, d6, d7);
        }
    }
    __syncthreads();

    const unsigned short* kr = kbufB + sub * 8;

    float logits[49];
    #pragma unroll
    for (int kk = 0; kk < 49; ++kk) {
        const int ky = kk / 7, kx = kk % 7;
        const int pp = (py + ky) * 14 + (px + kx);
        uint4 kv = *(const uint4*)(kr + pp * 40);
        float s = 0.f;
        s = dot2bf(kv.x, qv.x, s);
        s = dot2bf(kv.y, qv.y, s);
        s = dot2bf(kv.z, qv.z, s);
        s = dot2bf(kv.w, qv.w, s);
        logits[kk] = fmaf(qsum4(s), LOG2E, posE[ky + kx]);
    }

    float m = logits[0];
    #pragma unroll
    for (int kk = 1; kk < 49; ++kk) m = fmaxf(m, logits[kk]);
    float sum = 0.f;
    #pragma unroll
    for (int kk = 0; kk < 49; ++kk) {
        logits[kk] = __builtin_amdgcn_exp2f(logits[kk] - m);
        sum += logits[kk];
    }

    // PV: per window row, 4 pair-units x 8ch dot2h; both px parities share
    // pair base px>>1 (even: (w0,w1)(w2,w3)(w4,w5)(w6,0); odd: (0,w0)(w1,w2)...).
    const int e = px & 1, pb = px >> 1;
    const unsigned* vr = vpb + sub * 8;
    float a0=0,a1=0,a2=0,a3=0,a4=0,a5=0,a6=0,a7=0;
    #pragma unroll
    for (int ky = 0; ky < 7; ++ky) {
        const float* w = logits + ky * 7;
        float l0 = e ? 0.f  : w[0], h0 = e ? w[0] : w[1];
        float l1 = e ? w[1] : w[2], h1 = e ? w[2] : w[3];
        float l2 = e ? w[3] : w[4], h2 = e ? w[4] : w[5];
        float l3 = e ? w[5] : w[6], h3 = e ? w[6] : 0.f;
        unsigned wd0 = pkh(l0, h0), wd1 = pkh(l1, h1);
        unsigned wd2 = pkh(l2, h2), wd3 = pkh(l3, h3);
        const unsigned* vb = vr + ((py + ky) * 7 + pb) * 36;
        {
            const uint4* q4 = (const uint4*)vb;
            uint4 A = q4[0], B4 = q4[1];
            a0=dot2h(A.x,wd0,a0);  a1=dot2h(A.y,wd0,a1);
            a2=dot2h(A.z,wd0,a2);  a3=dot2h(A.w,wd0,a3);
            a4=dot2h(B4.x,wd0,a4); a5=dot2h(B4.y,wd0,a5);
            a6=dot2h(B4.z,wd0,a6); a7=dot2h(B4.w,wd0,a7);
        }
        {
            const uint4* q4 = (const uint4*)(vb + 36);
            uint4 A = q4[0], B4 = q4[1];
            a0=dot2h(A.x,wd1,a0);  a1=dot2h(A.y,wd1,a1);
            a2=dot2h(A.z,wd1,a2);  a3=dot2h(A.w,wd1,a3);
            a4=dot2h(B4.x,wd1,a4); a5=dot2h(B4.y,wd1,a5);
            a6=dot2h(B4.z,wd1,a6); a7=dot2h(B4.w,wd1,a7);
        }
        {
            const uint4* q4 = (const uint4*)(vb + 72);
            uint4 A = q4[0], B4 = q4[1];
            a0=dot2h(A.x,wd2,a0);  a1=dot2h(A.y,wd2,a1);
            a2=dot2h(A.z,wd2,a2);  a3=dot2h(A.w,wd2,a3);
            a4=dot2h(B4.x,wd2,a4); a5=dot2h(B4.y,wd2,a5);
            a6=dot2h(B4.z,wd2,a6); a7=dot2h(B4.w,wd2,a7);
        }
        {
            const uint4* q4 = (const uint4*)(vb + 108);
            uint4 A = q4[0], B4 = q4[1];
            a0=dot2h(A.x,wd3,a0);  a1=dot2h(A.y,wd3,a1);
            a2=dot2h(A.z,wd3,a2);  a3=dot2h(A.w,wd3,a3);
            a4=dot2h(B4.x,wd3,a4); a5=dot2h(B4.y,wd3,a5);
            a6=dot2h(B4.z,wd3,a6); a7=dot2h(B4.w,wd3,a7);
        }
    }
    const float inv = 1.f / sum;

    uint4 o;
    o.x = pack2(a0 * inv, a1 * inv);
    o.y = pack2(a2 * inv, a3 * inv);
    o.z = pack2(a4 * inv, a5 * inv);
    o.w = pack2(a6 * inv, a7 * inv);
    *(uint4*)(oact + (size_t)(bq * HW + p) * CIN + h * 32 + sub * 8) = o;
}

// ======================= Phase 3: projection tile ===========================
// t in [0,294): mt = t%3 (64 out ch), pt = t/3 (64-pixel strip).
__global__ __launch_bounds__(256) void k_p3(
    const float* __restrict__ wproj, const unsigned short* __restrict__ oact,
    float* __restrict__ out)
{
    extern __shared__ char smem[];
    unsigned short* As  = (unsigned short*)smem;
    unsigned short* Bs  = As + 64 * 200;
    unsigned*       Asw = (unsigned*)smem;

    const int tid = threadIdx.x;
    const int lane = tid & 63, wave = tid >> 6;
    const int l15  = lane & 15, quad = lane >> 4;
    const int wm   = (wave & 1) * 32, wn = (wave >> 1) * 32;

    const int t = blockIdx.x;
    const int mt = t % 3, pt = t / 3;
    {
        int o = tid >> 2, c4 = tid & 3;
        #pragma unroll
        for (int i = 0; i < 12; ++i) {
            int cq = c4 + 4 * i;
            float4 w = *(const float4*)(wproj + (size_t)(mt * 64 + o) * CIN + cq * 4);
            uint2 d; d.x = pack2(w.x, w.y); d.y = pack2(w.z, w.w);
            *(uint2*)(Asw + o * 100 + cq * 2) = d;
        }
    }
    {
        int rw = tid >> 2, s4 = tid & 3;
        #pragma unroll
        for (int i = 0; i < 6; ++i) {
            int seg = s4 + 4 * i;               // 0..23
            uint4 dv = *(const uint4*)(oact + (size_t)(pt * 64 + rw) * CIN + seg * 8);
            *(uint4*)(Bs + rw * 200 + seg * 8) = dv;
        }
    }
    __syncthreads();

    f32x4 acc[2][2] = {};
    const unsigned short* pa0 = As + (wm + l15) * 200 + quad * 8;
    const unsigned short* pb0 = Bs + (wn + l15) * 200 + quad * 8;
    #pragma unroll
    for (int s = 0; s < 6; ++s) {
        short8 a0 = *(const short8*)(pa0 + s * 32);
        short8 a1 = *(const short8*)(pa0 + 16 * 200 + s * 32);
        short8 b0 = *(const short8*)(pb0 + s * 32);
        short8 b1 = *(const short8*)(pb0 + 16 * 200 + s * 32);
        acc[0][0] = __builtin_amdgcn_mfma_f32_16x16x32_bf16(a0, b0, acc[0][0], 0, 0, 0);
        acc[0][1] = __builtin_amdgcn_mfma_f32_16x16x32_bf16(a0, b1, acc[0][1], 0, 0, 0);
        acc[1][0] = __builtin_amdgcn_mfma_f32_16x16x32_bf16(a1, b0, acc[1][0], 0, 0, 0);
        acc[1][1] = __builtin_amdgcn_mfma_f32_16x16x32_bf16(a1, b1, acc[1][1], 0, 0, 0);
    }

    const int bb = (pt * 64 >= HW) ? 1 : 0;
    const int pl = pt * 64 - bb * HW + wn + l15;      // col = pixel within batch
    const int go = mt * 64 + wm + quad * 4;           // row = output channel
    float* Yb = out + (size_t)bb * (CIN * HW);
    #pragma unroll
    for (int ti = 0; ti < 2; ++ti)
        #pragma unroll
        for (int tj = 0; tj < 2; ++tj)
            #pragma unroll
            for (int rr = 0; rr < 4; ++rr)
                Yb[(size_t)(go + ti * 16 + rr) * HW + pl + tj * 16] = acc[ti][tj][rr];
}

// ---------------------------------------------------------------------------
extern "C" void kernel_launch(void* const* d_in, const int* in_sizes, int n_in,
                              void* d_out, int out_size, void* d_ws, size_t ws_size,
                              hipStream_t stream)
{
    const float* x     = (const float*)d_in[0];
    const float* wq    = (const float*)d_in[1];
    const float* wk    = (const float*)d_in[2];
    const float* wv    = (const float*)d_in[3];
    const float* pos   = (const float*)d_in[4];
    const float* wproj = (const float*)d_in[5];

    char* ws = (char*)d_ws;
    unsigned short* qkvp  = (unsigned short*)ws;
    unsigned short* oactp = (unsigned short*)(ws + 7225344);
    float*          outp  = (float*)d_out;

    k_p1<<<dim3(882), dim3(256), SMEM_P1, stream>>>(x, wq, wk, wv, qkvp);
    k_p2<<<dim3(588), dim3(256), SMEM_P2, stream>>>(qkvp, pos, oactp);
    k_p3<<<dim3(294), dim3(256), SMEM_P1, stream>>>(wproj, oactp, outp);
}